// Round 1
// baseline (454.627 us; speedup 1.0000x reference)
//
#include <hip/hip_runtime.h>
#include <stdint.h>

typedef float  f32x4  __attribute__((ext_vector_type(4)));
typedef __bf16 bf16x8 __attribute__((ext_vector_type(8)));

#define AS1 __attribute__((address_space(1)))
#define AS3 __attribute__((address_space(3)))

// Problem constants
// B=2, S=2048, HID=2048, NH=16, HD=128, RING=4, CH=512, DIL=2
// packed length per (b,h,parity) = 1024; packed kv-chunk = 256

// ---------------- convert x: f32 -> bf16, 4 elems/thread ----------------
__global__ void k_cvt_x(const float* __restrict__ x, __bf16* __restrict__ y) {
  const int i = blockIdx.x * 256 + threadIdx.x;
  const float4 v = reinterpret_cast<const float4*>(x)[i];
  union { __bf16 b[4]; uint64_t u; } o;
  o.b[0] = (__bf16)v.x; o.b[1] = (__bf16)v.y; o.b[2] = (__bf16)v.z; o.b[3] = (__bf16)v.w;
  reinterpret_cast<uint64_t*>(y)[i] = o.u;
}

// ------- transpose+convert W[K][N] f32 -> Wt[N][K] bf16 (64x64 tiles) -------
__global__ void k_cvt_wt(const float* __restrict__ w, __bf16* __restrict__ wt,
                         const int K, const int N) {
  __shared__ float tile[64][65];
  const int k0 = blockIdx.x * 64, n0 = blockIdx.y * 64;
  const int t = threadIdx.x;
  #pragma unroll
  for (int i = 0; i < 16; ++i) {
    const int idx = t + 256 * i;
    const int r = idx >> 6, c = idx & 63;
    tile[r][c] = w[(size_t)(k0 + r) * N + n0 + c];
  }
  __syncthreads();
  #pragma unroll
  for (int i = 0; i < 16; ++i) {
    const int idx = t + 256 * i;
    const int r = idx >> 6, c = idx & 63;
    wt[(size_t)(n0 + r) * K + k0 + c] = (__bf16)tile[c][r];
  }
}

// ---------------- bt-GEMM: C[M][N] = A[M][K] * Bt[N][K]^T (bf16 in, f32 acc)
// EPI==1: scatter epilogue into parity-packed Q,K (s-major) and V (d-major)
// EPI==2: plain f32 row-major output
template<int EPI>
__global__ __launch_bounds__(256, 2) void k_gemm_bt(
    const __bf16* __restrict__ A, const __bf16* __restrict__ Bt,
    __bf16* __restrict__ Oq, __bf16* __restrict__ Ok, __bf16* __restrict__ Ov,
    float* __restrict__ Of, const int M, const int N, const int K) {
  __shared__ __bf16 As[128 * 32];
  __shared__ __bf16 Bs[128 * 32];
  const int tid = threadIdx.x;
  const int w = tid >> 6, l = tid & 63, g = l >> 4, l15 = l & 15;
  const int wr = w >> 1, wc = w & 1;
  const int m0 = blockIdx.y * 128, n0 = blockIdx.x * 128;
  const int srow = l >> 2, scol = (l & 3) * 8;   // staging: lane -> (row%16, col)

  f32x4 acc[4][4] = {};

  for (int kt = 0; kt < K; kt += 32) {
    __syncthreads();
    #pragma unroll
    for (int i = 0; i < 2; ++i) {
      const int ch = w * 2 + i;              // 1KB chunk id (wave-uniform)
      const int row = ch * 16 + srow;
      __builtin_amdgcn_global_load_lds(
          (const AS1 uint32_t*)(A + (size_t)(m0 + row) * K + kt + scol),
          (AS3 uint32_t*)(As + ch * 512), 16, 0, 0);
      __builtin_amdgcn_global_load_lds(
          (const AS1 uint32_t*)(Bt + (size_t)(n0 + row) * K + kt + scol),
          (AS3 uint32_t*)(Bs + ch * 512), 16, 0, 0);
    }
    __syncthreads();

    bf16x8 af[4], bfr[4];
    #pragma unroll
    for (int mi = 0; mi < 4; ++mi)
      af[mi] = *reinterpret_cast<const bf16x8*>(As + (wr * 64 + mi * 16 + l15) * 32 + 8 * g);
    #pragma unroll
    for (int ni = 0; ni < 4; ++ni)
      bfr[ni] = *reinterpret_cast<const bf16x8*>(Bs + (wc * 64 + ni * 16 + l15) * 32 + 8 * g);
    #pragma unroll
    for (int mi = 0; mi < 4; ++mi)
      #pragma unroll
      for (int ni = 0; ni < 4; ++ni)
        acc[mi][ni] = __builtin_amdgcn_mfma_f32_16x16x32_bf16(af[mi], bfr[ni], acc[mi][ni], 0, 0, 0);
  }

  if constexpr (EPI == 1) {
    // n block (128-wide, aligned) lies inside exactly one (t, h)
    const int t = n0 >> 11;                 // 0:q 1:k 2:v
    const int h = (n0 & 2047) >> 7;
    const int bb = m0 >> 11;
    #pragma unroll
    for (int mi = 0; mi < 4; ++mi) {
      #pragma unroll
      for (int r = 0; r < 4; ++r) {
        const int m = m0 + wr * 64 + mi * 16 + 4 * g + r;
        const int s = m & 2047;
        const int sp = s & 1, s2 = s >> 1;
        const size_t base = ((((size_t)bb * 16 + h) * 2 + sp) << 17);  // *131072
        #pragma unroll
        for (int ni = 0; ni < 4; ++ni) {
          const int d = wc * 64 + ni * 16 + l15;
          const __bf16 v = (__bf16)acc[mi][ni][r];
          if (t == 0)      Oq[base + (size_t)s2 * 128 + d] = v;
          else if (t == 1) Ok[base + (size_t)s2 * 128 + d] = v;
          else             Ov[base + (size_t)d * 1024 + s2] = v;
        }
      }
    }
  } else {
    #pragma unroll
    for (int mi = 0; mi < 4; ++mi)
      #pragma unroll
      for (int ni = 0; ni < 4; ++ni)
        #pragma unroll
        for (int r = 0; r < 4; ++r) {
          const int m = m0 + wr * 64 + mi * 16 + 4 * g + r;
          const int n = n0 + wc * 64 + ni * 16 + l15;
          Of[(size_t)m * N + n] = acc[mi][ni][r];
        }
  }
}

// ---------------- fused dilated ring attention (parity-packed) ----------------
// grid: 1024 blocks = b(2) x h(16) x p(2) x qt(16); 256 threads = 4 waves
// each wave owns 16 packed q-rows; per kv-chunk (256 packed cols):
//   S = Q K'^T (raw), per-row chunk max, e = exp2((S-m)*SC), den += rowsum,
//   E -> LDS (bf16), num += E @ V'  (V' pre-transposed d-major)
__global__ __launch_bounds__(256, 2) void k_attn(
    const __bf16* __restrict__ Qp, const __bf16* __restrict__ Kp,
    const __bf16* __restrict__ Vt, __bf16* __restrict__ attn) {
  __shared__ __bf16 E[64][264];   // +8 pad: 2-way-max bank conflict on b128 reads
  const int bx = blockIdx.x;
  const int qt = bx & 15, p = (bx >> 4) & 1, h = (bx >> 5) & 15, b = bx >> 9;
  const int tid = threadIdx.x;
  const int w = tid >> 6, l = tid & 63, g = l >> 4, l15 = l & 15;
  const size_t base = ((((size_t)b * 16 + h) * 2 + p) << 17);  // *131072
  const __bf16* Qb = Qp + base;
  const __bf16* Kb = Kp + base;
  const __bf16* Vb = Vt + base;
  const int q0 = qt * 64 + w * 16;
  const float SC = 1.4426950408889634f / 11.313708498984761f;  // log2(e)/sqrt(128)

  bf16x8 qf[4];
  #pragma unroll
  for (int ks = 0; ks < 4; ++ks)
    qf[ks] = *reinterpret_cast<const bf16x8*>(Qb + (size_t)(q0 + l15) * 128 + ks * 32 + 8 * g);

  f32x4 num[8] = {};
  float den[4] = {0.f, 0.f, 0.f, 0.f};

  for (int c = 0; c < 4; ++c) {
    // ---- scores: 16 rows x 256 cols per wave, K=128 ----
    f32x4 s[16] = {};
    #pragma unroll
    for (int ks = 0; ks < 4; ++ks) {
      #pragma unroll
      for (int nf = 0; nf < 16; ++nf) {
        const bf16x8 kf = *reinterpret_cast<const bf16x8*>(
            Kb + (size_t)(c * 256 + nf * 16 + l15) * 128 + ks * 32 + 8 * g);
        s[nf] = __builtin_amdgcn_mfma_f32_16x16x32_bf16(qf[ks], kf, s[nf], 0, 0, 0);
      }
    }
    // ---- per-chunk softmax (no rescale across chunks, matches reference) ----
    #pragma unroll
    for (int r = 0; r < 4; ++r) {
      float mv = s[0][r];
      #pragma unroll
      for (int nf = 1; nf < 16; ++nf) mv = fmaxf(mv, s[nf][r]);
      mv = fmaxf(mv, __shfl_xor(mv, 1));
      mv = fmaxf(mv, __shfl_xor(mv, 2));
      mv = fmaxf(mv, __shfl_xor(mv, 4));
      mv = fmaxf(mv, __shfl_xor(mv, 8));
      float ds = 0.f;
      #pragma unroll
      for (int nf = 0; nf < 16; ++nf) {
        const float e = exp2f((s[nf][r] - mv) * SC);
        s[nf][r] = e;
        ds += e;
      }
      ds += __shfl_xor(ds, 1);
      ds += __shfl_xor(ds, 2);
      ds += __shfl_xor(ds, 4);
      ds += __shfl_xor(ds, 8);
      den[r] += ds;
    }
    // ---- E -> LDS ----
    __syncthreads();   // prev chunk's PV reads done
    #pragma unroll
    for (int nf = 0; nf < 16; ++nf)
      #pragma unroll
      for (int r = 0; r < 4; ++r)
        E[w * 16 + 4 * g + r][nf * 16 + l15] = (__bf16)s[nf][r];
    __syncthreads();
    // ---- PV: num[16 x 128] += E[16 x 256] @ V'[256 x 128] ----
    #pragma unroll
    for (int ks = 0; ks < 8; ++ks) {
      const bf16x8 a = *reinterpret_cast<const bf16x8*>(&E[w * 16 + l15][ks * 32 + 8 * g]);
      #pragma unroll
      for (int nd = 0; nd < 8; ++nd) {
        const bf16x8 vf = *reinterpret_cast<const bf16x8*>(
            Vb + (size_t)(nd * 16 + l15) * 1024 + c * 256 + ks * 32 + 8 * g);
        num[nd] = __builtin_amdgcn_mfma_f32_16x16x32_bf16(a, vf, num[nd], 0, 0, 0);
      }
    }
  }

  // ---- epilogue: out[b, 2*s'+p, h*128+d] = num/den ----
  #pragma unroll
  for (int nd = 0; nd < 8; ++nd)
    #pragma unroll
    for (int r = 0; r < 4; ++r) {
      const int sq = q0 + 4 * g + r;          // packed index
      const int srow = 2 * sq + p;            // original sequence pos
      const float ov = num[nd][r] / (den[r] + 1e-8f);
      attn[((size_t)b * 2048 + srow) * 2048 + h * 128 + nd * 16 + l15] = (__bf16)ov;
    }
}

extern "C" void kernel_launch(void* const* d_in, const int* in_sizes, int n_in,
                              void* d_out, int out_size, void* d_ws, size_t ws_size,
                              hipStream_t stream) {
  (void)in_sizes; (void)n_in; (void)out_size; (void)ws_size;
  const float* x    = (const float*)d_in[0];
  const float* wqkv = (const float*)d_in[1];
  const float* wout = (const float*)d_in[2];
  float* out = (float*)d_out;
  uint8_t* ws = (uint8_t*)d_ws;

  // workspace layout (bytes); total needed = 96 MB
  __bf16* xbf   = (__bf16*)(ws + 0);                    // 16 MB [4096][2048]
  __bf16* wqkvt = (__bf16*)(ws + (16ull << 20));        // 24 MB [6144][2048]
  __bf16* woutt = (__bf16*)(ws + (40ull << 20));        //  8 MB [2048][2048]
  __bf16* Qp    = (__bf16*)(ws + (48ull << 20));        // 16 MB [b][h][p][1024][128]
  __bf16* Kp    = (__bf16*)(ws + (64ull << 20));        // 16 MB [b][h][p][1024][128]
  __bf16* Vt    = (__bf16*)(ws + (80ull << 20));        // 16 MB [b][h][p][128][1024]
  __bf16* attn  = (__bf16*)(ws + 0);                    // reuse xbf (dead after GEMM1)

  k_cvt_x<<<8192, 256, 0, stream>>>(x, xbf);
  k_cvt_wt<<<dim3(32, 96), 256, 0, stream>>>(wqkv, wqkvt, 2048, 6144);
  k_cvt_wt<<<dim3(32, 32), 256, 0, stream>>>(wout, woutt, 2048, 2048);
  // qkv projection, fused parity-pack + V-transpose epilogue
  k_gemm_bt<1><<<dim3(48, 32), 256, 0, stream>>>(xbf, wqkvt, Qp, Kp, Vt, nullptr, 4096, 6144, 2048);
  // fused dilated attention
  k_attn<<<1024, 256, 0, stream>>>(Qp, Kp, Vt, attn);
  // output projection -> f32
  k_gemm_bt<2><<<dim3(16, 32), 256, 0, stream>>>(attn, woutt, nullptr, nullptr, nullptr, out, 4096, 2048, 2048);
}

// Round 3
// 396.820 us; speedup vs baseline: 1.1457x; 1.1457x over previous
//
#include <hip/hip_runtime.h>
#include <stdint.h>

typedef float  f32x4  __attribute__((ext_vector_type(4)));
typedef __bf16 bf16x8 __attribute__((ext_vector_type(8)));

#define AS1 __attribute__((address_space(1)))
#define AS3 __attribute__((address_space(3)))

// Problem constants
// B=2, S=2048, HID=2048, NH=16, HD=128, RING=4, CH=512, DIL=2
// packed length per (b,h,parity) = 1024; packed kv-chunk = 256

// ---------------- convert x: f32 -> bf16, 4 elems/thread ----------------
__global__ void k_cvt_x(const float* __restrict__ x, __bf16* __restrict__ y) {
  const int i = blockIdx.x * 256 + threadIdx.x;
  const float4 v = reinterpret_cast<const float4*>(x)[i];
  union { __bf16 b[4]; uint64_t u; } o;
  o.b[0] = (__bf16)v.x; o.b[1] = (__bf16)v.y; o.b[2] = (__bf16)v.z; o.b[3] = (__bf16)v.w;
  reinterpret_cast<uint64_t*>(y)[i] = o.u;
}

// ------- transpose+convert W[K][N] f32 -> Wt[N][K] bf16 (64x64 tiles) -------
__global__ void k_cvt_wt(const float* __restrict__ w, __bf16* __restrict__ wt,
                         const int K, const int N) {
  __shared__ float tile[64][65];
  const int k0 = blockIdx.x * 64, n0 = blockIdx.y * 64;
  const int t = threadIdx.x;
  #pragma unroll
  for (int i = 0; i < 16; ++i) {
    const int idx = t + 256 * i;
    const int r = idx >> 6, c = idx & 63;
    tile[r][c] = w[(size_t)(k0 + r) * N + n0 + c];
  }
  __syncthreads();
  #pragma unroll
  for (int i = 0; i < 16; ++i) {
    const int idx = t + 256 * i;
    const int r = idx >> 6, c = idx & 63;
    wt[(size_t)(n0 + r) * K + k0 + c] = (__bf16)tile[c][r];
  }
}

// ---------------- bt-GEMM: C[M][N] = A[M][K] * Bt[N][K]^T (bf16 in, f32 acc)
// EPI==1: scatter epilogue into parity-packed Q,K (s-major) and V (d-major)
// EPI==2: plain f32 row-major output
template<int EPI>
__global__ __launch_bounds__(256, 2) void k_gemm_bt(
    const __bf16* __restrict__ A, const __bf16* __restrict__ Bt,
    __bf16* __restrict__ Oq, __bf16* __restrict__ Ok, __bf16* __restrict__ Ov,
    float* __restrict__ Of, const int M, const int N, const int K) {
  __shared__ __bf16 As[128 * 32];
  __shared__ __bf16 Bs[128 * 32];
  const int tid = threadIdx.x;
  const int w = tid >> 6, l = tid & 63, g = l >> 4, l15 = l & 15;
  const int wr = w >> 1, wc = w & 1;
  const int m0 = blockIdx.y * 128, n0 = blockIdx.x * 128;
  const int srow = l >> 2, scol = (l & 3) * 8;   // staging: lane -> (row%16, col)

  f32x4 acc[4][4] = {};

  for (int kt = 0; kt < K; kt += 32) {
    __syncthreads();
    #pragma unroll
    for (int i = 0; i < 2; ++i) {
      const int ch = w * 2 + i;              // 1KB chunk id (wave-uniform)
      const int row = ch * 16 + srow;
      __builtin_amdgcn_global_load_lds(
          (const AS1 uint32_t*)(A + (size_t)(m0 + row) * K + kt + scol),
          (AS3 uint32_t*)(As + ch * 512), 16, 0, 0);
      __builtin_amdgcn_global_load_lds(
          (const AS1 uint32_t*)(Bt + (size_t)(n0 + row) * K + kt + scol),
          (AS3 uint32_t*)(Bs + ch * 512), 16, 0, 0);
    }
    __syncthreads();

    bf16x8 af[4], bfr[4];
    #pragma unroll
    for (int mi = 0; mi < 4; ++mi)
      af[mi] = *reinterpret_cast<const bf16x8*>(As + (wr * 64 + mi * 16 + l15) * 32 + 8 * g);
    #pragma unroll
    for (int ni = 0; ni < 4; ++ni)
      bfr[ni] = *reinterpret_cast<const bf16x8*>(Bs + (wc * 64 + ni * 16 + l15) * 32 + 8 * g);
    #pragma unroll
    for (int mi = 0; mi < 4; ++mi)
      #pragma unroll
      for (int ni = 0; ni < 4; ++ni)
        acc[mi][ni] = __builtin_amdgcn_mfma_f32_16x16x32_bf16(af[mi], bfr[ni], acc[mi][ni], 0, 0, 0);
  }

  if constexpr (EPI == 1) {
    // n block (128-wide, aligned) lies inside exactly one (t, h)
    const int t = n0 >> 11;                 // 0:q 1:k 2:v
    const int h = (n0 & 2047) >> 7;
    const int bb = m0 >> 11;
    #pragma unroll
    for (int mi = 0; mi < 4; ++mi) {
      #pragma unroll
      for (int r = 0; r < 4; ++r) {
        const int m = m0 + wr * 64 + mi * 16 + 4 * g + r;
        const int s = m & 2047;
        const int sp = s & 1, s2 = s >> 1;
        const size_t base = ((((size_t)bb * 16 + h) * 2 + sp) << 17);  // *131072
        #pragma unroll
        for (int ni = 0; ni < 4; ++ni) {
          const int d = wc * 64 + ni * 16 + l15;
          const __bf16 v = (__bf16)acc[mi][ni][r];
          if (t == 0)      Oq[base + (size_t)s2 * 128 + d] = v;
          else if (t == 1) Ok[base + (size_t)s2 * 128 + d] = v;
          else             Ov[base + (size_t)d * 1024 + s2] = v;
        }
      }
    }
  } else {
    #pragma unroll
    for (int mi = 0; mi < 4; ++mi)
      #pragma unroll
      for (int ni = 0; ni < 4; ++ni)
        #pragma unroll
        for (int r = 0; r < 4; ++r) {
          const int m = m0 + wr * 64 + mi * 16 + 4 * g + r;
          const int n = n0 + wc * 64 + ni * 16 + l15;
          Of[(size_t)m * N + n] = acc[mi][ni][r];
        }
  }
}

// ---------------- fused dilated ring attention (parity-packed) ----------------
// grid: 1024 blocks; XCD-chunked remap so all 16 q-tiles of one (b,h,p) share
// one XCD's L2 (512 KB K+V panel; 8 panels = 4 MB = one L2).
// 256 threads = 4 waves; each wave owns 16 packed q-rows.
// K is LDS-staged per 64-row subtile (global_load_lds w16, m97 2-barrier
// structure) with T2 XOR swizzle applied via pre-swizzled GLOBAL source
// (gload_lds dest must stay linear). V read from global (XCD-local L2).
__global__ __launch_bounds__(256, 4) void k_attn(
    const __bf16* __restrict__ Qp, const __bf16* __restrict__ Kp,
    const __bf16* __restrict__ Vt, __bf16* __restrict__ attn) {
  __shared__ __bf16 Ks[64 * 128];   // 16 KB K subtile, XOR-swizzled layout
  __shared__ __bf16 E[64][136];     // 17 KB half-chunk E (+8 pad)
  // XCD-chunked block remap: hw XCD = blockIdx.x % 8 (round-robin dispatch)
  const int wid = (blockIdx.x & 7) * 128 + (blockIdx.x >> 3);
  const int qt = wid & 15, p = (wid >> 4) & 1, h = (wid >> 5) & 15, b = wid >> 9;
  const int tid = threadIdx.x;
  const int w = tid >> 6, l = tid & 63, g = l >> 4, l15 = l & 15;
  const size_t base = ((((size_t)b * 16 + h) * 2 + p) << 17);  // *131072
  const __bf16* Qb = Qp + base;
  const __bf16* Kb = Kp + base;
  const __bf16* Vb = Vt + base;
  const int q0 = qt * 64 + w * 16;
  const float SC = 1.4426950408889634f / 11.313708498984761f;  // log2(e)/sqrt(128)

  bf16x8 qf[4];
  #pragma unroll
  for (int ks = 0; ks < 4; ++ks)
    qf[ks] = *reinterpret_cast<const bf16x8*>(Qb + (size_t)(q0 + l15) * 128 + ks * 32 + 8 * g);

  f32x4 num[8] = {};
  float den[4] = {0.f, 0.f, 0.f, 0.f};

  for (int c = 0; c < 4; ++c) {
    f32x4 s[16] = {};   // zero-init; MFMA accumulates over ks (C-in AND C-out)
    // ---- QK^T over 4 K-subtiles of 64 rows, LDS-staged ----
    #pragma unroll
    for (int st = 0; st < 4; ++st) {
      __syncthreads();   // Ks readers from previous subtile done
      #pragma unroll
      for (int i = 0; i < 4; ++i) {
        const int ch = w * 4 + i;                  // wave-uniform chunk id
        const int row = ch * 4 + (l >> 4);         // 0..63 within subtile
        const int cb = (l15 * 16) ^ ((row & 7) << 4);
        const __bf16* src = Kb + (size_t)(c * 256 + st * 64 + row) * 128 + (cb >> 1);
        __builtin_amdgcn_global_load_lds((const AS1 uint32_t*)src,
                                         (AS3 uint32_t*)(Ks + ch * 512), 16, 0, 0);
      }
      __syncthreads();   // staging landed (vmcnt0 drain at barrier)
      #pragma unroll
      for (int ks = 0; ks < 4; ++ks) {
        #pragma unroll
        for (int nf2 = 0; nf2 < 4; ++nf2) {
          const int r = nf2 * 16 + l15;            // row within subtile
          const int cb = (ks * 64 + g * 16) ^ ((r & 7) << 4);
          const bf16x8 kf = *reinterpret_cast<const bf16x8*>(Ks + r * 128 + (cb >> 1));
          s[st * 4 + nf2] = __builtin_amdgcn_mfma_f32_16x16x32_bf16(qf[ks], kf, s[st * 4 + nf2], 0, 0, 0);
        }
      }
    }
    // ---- per-chunk softmax (no rescale across chunks, matches reference) ----
    #pragma unroll
    for (int r = 0; r < 4; ++r) {
      float mv = s[0][r];
      #pragma unroll
      for (int nf = 1; nf < 16; ++nf) mv = fmaxf(mv, s[nf][r]);
      mv = fmaxf(mv, __shfl_xor(mv, 1));
      mv = fmaxf(mv, __shfl_xor(mv, 2));
      mv = fmaxf(mv, __shfl_xor(mv, 4));
      mv = fmaxf(mv, __shfl_xor(mv, 8));
      float ds = 0.f;
      #pragma unroll
      for (int nf = 0; nf < 16; ++nf) {
        const float e = exp2f((s[nf][r] - mv) * SC);
        s[nf][r] = e;
        ds += e;
      }
      ds += __shfl_xor(ds, 1);
      ds += __shfl_xor(ds, 2);
      ds += __shfl_xor(ds, 4);
      ds += __shfl_xor(ds, 8);
      den[r] += ds;
    }
    // ---- PV in two 128-col halves through half-size E buffer ----
    #pragma unroll
    for (int h2 = 0; h2 < 2; ++h2) {
      __syncthreads();   // E readers (prev half / prev chunk) done
      #pragma unroll
      for (int nf = 0; nf < 8; ++nf)
        #pragma unroll
        for (int r = 0; r < 4; ++r)
          E[w * 16 + 4 * g + r][nf * 16 + l15] = (__bf16)s[h2 * 8 + nf][r];
      __syncthreads();
      #pragma unroll
      for (int ks2 = 0; ks2 < 4; ++ks2) {
        const bf16x8 a = *reinterpret_cast<const bf16x8*>(&E[w * 16 + l15][ks2 * 32 + 8 * g]);
        #pragma unroll
        for (int nd = 0; nd < 8; ++nd) {
          const bf16x8 vf = *reinterpret_cast<const bf16x8*>(
              Vb + (size_t)(nd * 16 + l15) * 1024 + c * 256 + h2 * 128 + ks2 * 32 + 8 * g);
          num[nd] = __builtin_amdgcn_mfma_f32_16x16x32_bf16(a, vf, num[nd], 0, 0, 0);
        }
      }
    }
  }

  // ---- epilogue: out[b, 2*s'+p, h*128+d] = num/den ----
  #pragma unroll
  for (int nd = 0; nd < 8; ++nd)
    #pragma unroll
    for (int r = 0; r < 4; ++r) {
      const int sq = q0 + 4 * g + r;          // packed index
      const int srow = 2 * sq + p;            // original sequence pos
      const float ov = num[nd][r] / (den[r] + 1e-8f);
      attn[((size_t)b * 2048 + srow) * 2048 + h * 128 + nd * 16 + l15] = (__bf16)ov;
    }
}

extern "C" void kernel_launch(void* const* d_in, const int* in_sizes, int n_in,
                              void* d_out, int out_size, void* d_ws, size_t ws_size,
                              hipStream_t stream) {
  (void)in_sizes; (void)n_in; (void)out_size; (void)ws_size;
  const float* x    = (const float*)d_in[0];
  const float* wqkv = (const float*)d_in[1];
  const float* wout = (const float*)d_in[2];
  float* out = (float*)d_out;
  uint8_t* ws = (uint8_t*)d_ws;

  // workspace layout (bytes); total needed = 96 MB
  __bf16* xbf   = (__bf16*)(ws + 0);                    // 16 MB [4096][2048]
  __bf16* wqkvt = (__bf16*)(ws + (16ull << 20));        // 24 MB [6144][2048]
  __bf16* woutt = (__bf16*)(ws + (40ull << 20));        //  8 MB [2048][2048]
  __bf16* Qp    = (__bf16*)(ws + (48ull << 20));        // 16 MB [b][h][p][1024][128]
  __bf16* Kp    = (__bf16*)(ws + (64ull << 20));        // 16 MB [b][h][p][1024][128]
  __bf16* Vt    = (__bf16*)(ws + (80ull << 20));        // 16 MB [b][h][p][128][1024]
  __bf16* attn  = (__bf16*)(ws + 0);                    // reuse xbf (dead after GEMM1)

  k_cvt_x<<<8192, 256, 0, stream>>>(x, xbf);
  k_cvt_wt<<<dim3(32, 96), 256, 0, stream>>>(wqkv, wqkvt, 2048, 6144);
  k_cvt_wt<<<dim3(32, 32), 256, 0, stream>>>(wout, woutt, 2048, 2048);
  // qkv projection, fused parity-pack + V-transpose epilogue
  k_gemm_bt<1><<<dim3(48, 32), 256, 0, stream>>>(xbf, wqkvt, Qp, Kp, Vt, nullptr, 4096, 6144, 2048);
  // fused dilated attention
  k_attn<<<1024, 256, 0, stream>>>(Qp, Kp, Vt, attn);
  // output projection -> f32
  k_gemm_bt<2><<<dim3(16, 32), 256, 0, stream>>>(attn, woutt, nullptr, nullptr, nullptr, out, 4096, 2048, 2048);
}